// Round 6
// baseline (295.326 us; speedup 1.0000x reference)
//
#include <hip/hip_runtime.h>
#include <math.h>

#define IMG   1024
#define TILE  64
#define HALO  12
#define BW    88            // TILE + 2*HALO px per side
#define SP    48            // row stride in 32-bit words: 2 pad + 44 data + 2 pad
#define LDSN  (88*SP)       // 4224 words = 16896 B per buffer (rows 0..87, no guards)
#define IW0   8             // first interior word (px col 12 -> word 2 + 12/2 = 8)
#define SEN2  0x40004000u   // half2(2.0,2.0): +inf sentinel (all real values <= 1)

typedef _Float16 h2 __attribute__((ext_vector_type(2)));

union UH { unsigned u; h2 h; };
__device__ __forceinline__ h2 u2h(unsigned u){ UH x; x.u = u; return x.h; }
__device__ __forceinline__ unsigned h2u(h2 h){ UH x; x.h = h; return x.u; }
__device__ __forceinline__ h2 pmin(h2 a, h2 b){ return __builtin_elementwise_min(a, b); }
__device__ __forceinline__ h2 pmax(h2 a, h2 b){ return __builtin_elementwise_max(a, b); }
// (lo_src.hi, hi_src.lo) — one v_alignbit_b32
__device__ __forceinline__ h2 funnel(h2 hi_src, h2 lo_src){
  return u2h((h2u(lo_src) >> 16) | (h2u(hi_src) << 16));
}
__device__ __forceinline__ void u4h(uint4 v, h2* o){
  o[0] = u2h(v.x); o[1] = u2h(v.y); o[2] = u2h(v.z); o[3] = u2h(v.w);
}
__device__ __forceinline__ float sigmoidf(float x){ return 1.0f / (1.0f + __expf(-x)); }

// 5-pt cross erode of 8 px (4 words, 16B-aligned) at word offset `off`.
// 3 b128 + 2 b32 reads, 1 b128 write, 5 alignbit + 16 pk_min.
__device__ __forceinline__ void erode_quad(const unsigned* A, unsigned* B, int off){
  uint4 c = *(const uint4*)&A[off];
  uint4 u = *(const uint4*)&A[off - SP];
  uint4 d = *(const uint4*)&A[off + SP];
  unsigned pv = A[off - 1], nx = A[off + 4];
  h2 w0 = u2h(c.x), w1 = u2h(c.y), w2 = u2h(c.z), w3 = u2h(c.w);
  h2 v0 = pmin(u2h(u.x), u2h(d.x)), v1 = pmin(u2h(u.y), u2h(d.y));
  h2 v2 = pmin(u2h(u.z), u2h(d.z)), v3 = pmin(u2h(u.w), u2h(d.w));
  h2 L0 = funnel(w0, u2h(pv)), L1 = funnel(w1, w0), L2 = funnel(w2, w1),
     L3 = funnel(w3, w2), L4 = funnel(u2h(nx), w3);
  uint4 e;
  e.x = h2u(pmin(pmin(pmin(L0, L1), v0), w0));
  e.y = h2u(pmin(pmin(pmin(L1, L2), v1), w1));
  e.z = h2u(pmin(pmin(pmin(L2, L3), v2), w2));
  e.w = h2u(pmin(pmin(pmin(L3, L4), v3), w3));
  *(uint4*)&B[off] = e;
}

// soft_skeleton of one 64x64 tile (+12 halo), packed fp16 in LDS.
// MODE 0: sigmoid(pred); MODE 1: (float)target.  BND: tile touches image edge.
// Erode at step j covers rows [j, 87-j], full width; garbage fills ring < j,
// and e_j is only consumed at ring >= j (dilate consumes ring >= 11).
template<int MODE, bool BND>
__device__ void run_skel(const float* __restrict__ pred, const int* __restrict__ targ,
                         long base, int gr0, int gc0, int tid,
                         unsigned* A, unsigned* B, h2 val[8], h2 skel[8]) {
  // ---- global -> LDS ----
  if (!BND) {
    const int q  = tid & 31;
    const int rr = tid >> 5;
    #pragma unroll
    for (int k = 0; k < 11; ++k) {
      int r = rr + (k << 3);                       // 0..87
      if (q < 22) {                                // 22 x 4 px = 88 cols
        long gbase = base + (long)(gr0 + r) * IMG + gc0;
        unsigned lo, hi;
        if (MODE == 0) {
          float4 v = ((const float4*)(pred + gbase))[q];
          h2 a = {(_Float16)sigmoidf(v.x), (_Float16)sigmoidf(v.y)};
          h2 b = {(_Float16)sigmoidf(v.z), (_Float16)sigmoidf(v.w)};
          lo = h2u(a); hi = h2u(b);
        } else {
          int4 v = ((const int4*)(targ + gbase))[q];
          h2 a = {(_Float16)(float)v.x, (_Float16)(float)v.y};
          h2 b = {(_Float16)(float)v.z, (_Float16)(float)v.w};
          lo = h2u(a); hi = h2u(b);
        }
        uint2 w; w.x = lo; w.y = hi;
        *(uint2*)&A[r * SP + 2 + (q << 1)] = w;
      }
    }
  } else {
    const int q  = tid & 31;
    const int rr = tid >> 5;
    _Float16* Ah = (_Float16*)A;
    #pragma unroll
    for (int k = 0; k < 11; ++k) {
      int r = rr + (k << 3);
      int gr = gr0 + r;
      bool rok = (unsigned)gr < (unsigned)IMG;
      #pragma unroll
      for (int m = 0; m < 3; ++m) {
        int c = q + (m << 5);
        if (c < BW) {
          int gc = gc0 + c;
          _Float16 hv = (_Float16)2.0f;            // +inf sentinel
          if (rok && (unsigned)gc < (unsigned)IMG) {
            float f = (MODE == 0) ? sigmoidf(pred[base + (long)gr * IMG + gc])
                                  : (float)targ[base + (long)gr * IMG + gc];
            hv = (_Float16)f;
          }
          Ah[r * (SP * 2) + 4 + c] = hv;           // word 2 + c/2
        }
      }
    }
  }
  __syncthreads();

  // dilate/interior ownership: 4 words x 2 rows per thread
  const int qc = tid & 7;                 // quad col 0..7
  const int rg = tid >> 3;                // 0..31
  const int r0 = 12 + (rg << 1);          // rows r0, r0+1 in 12..75
  const int wq = IW0 + (qc << 2);         // words 8..36

  h2 ep[8];                               // e_{j-1} at own 16 px
  {
    uint4 a0 = *(const uint4*)&A[r0 * SP + wq];
    uint4 a1 = *(const uint4*)&A[(r0 + 1) * SP + wq];
    u4h(a0, ep); u4h(a1, ep + 4);
    #pragma unroll
    for (int i = 0; i < 8; ++i) val[i] = ep[i];
  }

  const h2 onev  = {(_Float16)1.0f, (_Float16)1.0f};
  const h2 zerov = {(_Float16)0.0f, (_Float16)0.0f};

  for (int j = 1; j <= 11; ++j) {
    // ---- erode A -> B, rows [j, 87-j] ----
    const int nq = (88 - 2 * j) * 12;
    const int rb = j * SP + (tid << 2);
    #pragma unroll
    for (int k = 0; k < 5; ++k)
      if (tid + (k << 8) < nq) erode_quad(A, B, rb + (k << 10));
    __syncthreads();

    if (BND) {
      // re-stamp out-of-image rows/cols to +inf sentinel
      if (gr0 < 0)        for (int i = tid; i < 12 * SP; i += 256) B[i] = SEN2;
      if (gr0 + BW > IMG) for (int i = tid; i < 12 * SP; i += 256) B[76 * SP + i] = SEN2;
      if (gc0 < 0)        for (int i = tid; i < 88 * 6; i += 256) { int r5 = i / 6; B[r5 * SP + 2 + (i - r5 * 6)] = SEN2; }
      if (gc0 + BW > IMG) for (int i = tid; i < 88 * 6; i += 256) { int r5 = i / 6; B[r5 * SP + 40 + (i - r5 * 6)] = SEN2; }
      __syncthreads();
    }

    // ---- 3x3 dilate of B at own 16 px + skel update ----
    h2 H[4][4];
    uint4 en0, en1;
    #pragma unroll
    for (int k = 0; k < 4; ++k) {
      const int ro = (r0 - 1 + k) * SP + wq;
      uint4 cw = *(const uint4*)&B[ro];
      unsigned pvu = B[ro - 1], nxu = B[ro + 4];
      if (k == 1) en0 = cw;                // raw e_j at own rows -> next ep
      if (k == 2) en1 = cw;
      h2 w[4]; u4h(cw, w);
      h2 e0 = u2h(pvu), e1 = u2h(nxu);
      if (BND) {
        // sentinel(2.0)->0, identity on [0,1]: t=max(x-1,0); x -= 2t (exact fp16)
        h2 t;
        t = pmax(w[0] - onev, zerov); w[0] = w[0] - t - t;
        t = pmax(w[1] - onev, zerov); w[1] = w[1] - t - t;
        t = pmax(w[2] - onev, zerov); w[2] = w[2] - t - t;
        t = pmax(w[3] - onev, zerov); w[3] = w[3] - t - t;
        t = pmax(e0 - onev, zerov);   e0 = e0 - t - t;
        t = pmax(e1 - onev, zerov);   e1 = e1 - t - t;
      }
      h2 L0 = funnel(w[0], e0), L1 = funnel(w[1], w[0]), L2 = funnel(w[2], w[1]),
         L3 = funnel(w[3], w[2]), L4 = funnel(e1, w[3]);
      H[k][0] = pmax(pmax(L0, L1), w[0]);
      H[k][1] = pmax(pmax(L1, L2), w[1]);
      H[k][2] = pmax(pmax(L2, L3), w[2]);
      H[k][3] = pmax(pmax(L3, L4), w[3]);
    }
    #pragma unroll
    for (int i = 0; i < 4; ++i) {
      h2 m0 = pmax(pmax(H[0][i], H[1][i]), H[2][i]);
      h2 m1 = pmax(pmax(H[1][i], H[2][i]), H[3][i]);
      h2 d0 = pmax(ep[i]     - m0, zerov);          // relu(e_prev - open)
      h2 d1 = pmax(ep[4 + i] - m1, zerov);
      if (j == 1) { skel[i] = d0; skel[4 + i] = d1; }
      else {
        h2 t0 = d0 - skel[i] * d0;
        h2 t1 = d1 - skel[4 + i] * d1;
        skel[i]     = skel[i]     + pmax(t0, zerov);
        skel[4 + i] = skel[4 + i] + pmax(t1, zerov);
      }
    }
    u4h(en0, ep); u4h(en1, ep + 4);
    __syncthreads();
    unsigned* t = A; A = B; B = t;
  }
}

__global__ __launch_bounds__(256)
void cl_dice_main(const float* __restrict__ pred, const int* __restrict__ targ,
                  float* __restrict__ ws) {
  __shared__ alignas(16) unsigned sA[LDSN];
  __shared__ alignas(16) unsigned sB[LDSN];
  const int tid = threadIdx.x;
  const int gr0 = blockIdx.y * TILE - HALO;
  const int gc0 = blockIdx.x * TILE - HALO;
  const long base = (long)blockIdx.z * (long)(IMG * IMG);

  h2 vp[8], kp[8], vt[8], kt[8];
  const bool bnd = (blockIdx.x == 0) | (blockIdx.x == gridDim.x - 1) |
                   (blockIdx.y == 0) | (blockIdx.y == gridDim.y - 1);
  if (!bnd) {
    run_skel<0, false>(pred, targ, base, gr0, gc0, tid, sA, sB, vp, kp);
    run_skel<1, false>(pred, targ, base, gr0, gc0, tid, sA, sB, vt, kt);
  } else {
    run_skel<0, true >(pred, targ, base, gr0, gc0, tid, sA, sB, vp, kp);
    run_skel<1, true >(pred, targ, base, gr0, gc0, tid, sA, sB, vt, kt);
  }

  float s[7] = {0, 0, 0, 0, 0, 0, 0};
  #pragma unroll
  for (int k = 0; k < 8; ++k) {
    float px = (float)vp[k].x, py = (float)vp[k].y;
    float tx = (float)vt[k].x, ty = (float)vt[k].y;
    float ax = (float)kp[k].x, ay = (float)kp[k].y;
    float bx = (float)kt[k].x, by = (float)kt[k].y;
    s[0] += ax + ay;
    s[1] += ax * tx + ay * ty;
    s[2] += bx + by;
    s[3] += bx * px + by * py;
    s[4] += px * tx + py * ty;
    s[5] += px + py;
    s[6] += tx + ty;
  }

  float* red = (float*)sA;
  #pragma unroll
  for (int k = 0; k < 7; ++k) {
    float v = s[k];
    v += __shfl_down(v, 32); v += __shfl_down(v, 16); v += __shfl_down(v, 8);
    v += __shfl_down(v, 4);  v += __shfl_down(v, 2);  v += __shfl_down(v, 1);
    if ((tid & 63) == 0) red[(tid >> 6) * 8 + k] = v;
  }
  __syncthreads();
  if (tid < 7) {
    float v = red[tid] + red[8 + tid] + red[16 + tid] + red[24 + tid];
    int blk = (blockIdx.z * gridDim.y + blockIdx.y) * gridDim.x + blockIdx.x;
    ws[blk * 8 + tid] = v;
  }
}

__global__ __launch_bounds__(256)
void cl_dice_finalize(const float* __restrict__ ws, float* __restrict__ out, int nblk) {
  __shared__ float red[4][8];
  int tid = threadIdx.x;
  float acc[7] = {0, 0, 0, 0, 0, 0, 0};
  for (int i = tid; i < nblk; i += 256) {
    #pragma unroll
    for (int k = 0; k < 7; ++k) acc[k] += ws[i * 8 + k];
  }
  #pragma unroll
  for (int k = 0; k < 7; ++k) {
    float v = acc[k];
    v += __shfl_down(v, 32); v += __shfl_down(v, 16); v += __shfl_down(v, 8);
    v += __shfl_down(v, 4);  v += __shfl_down(v, 2);  v += __shfl_down(v, 1);
    if ((tid & 63) == 0) red[tid >> 6][k] = v;
  }
  __syncthreads();
  if (tid == 0) {
    float t0[7];
    #pragma unroll
    for (int k = 0; k < 7; ++k)
      t0[k] = red[0][k] + red[1][k] + red[2][k] + red[3][k];
    float sum_sp = t0[0], sum_spt = t0[1], sum_st = t0[2], sum_stp = t0[3];
    float inter  = t0[4], sum_p   = t0[5], sum_t  = t0[6];
    float tprec = (sum_spt + 1.0f) / (sum_sp + 1.0f);
    float tsens = (sum_stp + 1.0f) / (sum_st + 1.0f);
    float cl    = 2.0f * tprec * tsens / (tprec + tsens + 1e-7f);
    float dice  = (2.0f * inter + 1.0f) / (sum_p + sum_t + 1.0f);
    out[0] = 1.0f - 0.5f * (dice + cl);
  }
}

extern "C" void kernel_launch(void* const* d_in, const int* in_sizes, int n_in,
                              void* d_out, int out_size, void* d_ws, size_t ws_size,
                              hipStream_t stream) {
  const float* pred = (const float*)d_in[0];
  const int*   targ = (const int*)d_in[1];
  float* ws  = (float*)d_ws;
  float* out = (float*)d_out;

  const int B = in_sizes[0] / (IMG * IMG);       // 8
  dim3 grid(IMG / TILE, IMG / TILE, B);          // 16 x 16 x 8 = 2048 blocks
  cl_dice_main<<<grid, 256, 0, stream>>>(pred, targ, ws);

  const int nblk = (IMG / TILE) * (IMG / TILE) * B;
  cl_dice_finalize<<<1, 256, 0, stream>>>(ws, out, nblk);
}

// Round 7
// 268.908 us; speedup vs baseline: 1.0982x; 1.0982x over previous
//
#include <hip/hip_runtime.h>
#include <math.h>

#define IMG  1024
#define TILE 64
#define HALO 12
#define SP   92             // words/row: 4 front pad + 88 data; 92%32=28 rotates banks
#define LDSW (88*SP)        // 8096 words = 32384 B per buffer; x2 = 64768 B (< 64K limit)
#define SEN2 0x40004000u    // (2.0h,2.0h) sentinel = +inf (all real values <= 1)

// One 32-bit word per pixel: lo half = pred, hi half = target. Both images
// undergo identical min/max/arith ops -> one fused pass, pk ops do both.
typedef _Float16 h2 __attribute__((ext_vector_type(2)));
union UH { unsigned u; h2 h; };
__device__ __forceinline__ h2 u2h(unsigned u){ UH x; x.u = u; return x.h; }
__device__ __forceinline__ unsigned h2u(h2 h){ UH x; x.h = h; return x.u; }
__device__ __forceinline__ h2 pmin(h2 a, h2 b){ return __builtin_elementwise_min(a, b); }
__device__ __forceinline__ h2 pmax(h2 a, h2 b){ return __builtin_elementwise_max(a, b); }
__device__ __forceinline__ float sigmoidf(float x){ return 1.0f / (1.0f + __expf(-x)); }

// 5-pt cross erode of a 4-word x 2-row strip at word offset o (16B aligned).
// All-b128: 8 reads + 2 writes; edge words come from adjacent aligned quads
// (their cross-row garbage lands only on ring-0 pixels).
__device__ __forceinline__ void erode2(const unsigned* A, unsigned* B, int o){
  uint4 up = *(const uint4*)&A[o - SP];
  uint4 c0 = *(const uint4*)&A[o];
  uint4 c1 = *(const uint4*)&A[o + SP];
  uint4 dn = *(const uint4*)&A[o + 2*SP];
  uint4 l0 = *(const uint4*)&A[o - 4];
  uint4 l1 = *(const uint4*)&A[o + SP - 4];
  uint4 r0 = *(const uint4*)&A[o + 4];
  uint4 r1 = *(const uint4*)&A[o + SP + 4];
  h2 a0=u2h(c0.x), a1=u2h(c0.y), a2=u2h(c0.z), a3=u2h(c0.w);
  h2 b0=u2h(c1.x), b1=u2h(c1.y), b2=u2h(c1.z), b3=u2h(c1.w);
  h2 v0=pmin(u2h(up.x),b0), v1=pmin(u2h(up.y),b1), v2=pmin(u2h(up.z),b2), v3=pmin(u2h(up.w),b3);
  h2 w0=pmin(a0,u2h(dn.x)), w1=pmin(a1,u2h(dn.y)), w2=pmin(a2,u2h(dn.z)), w3=pmin(a3,u2h(dn.w));
  uint4 e0, e1;
  e0.x = h2u(pmin(pmin(u2h(l0.w), a1), pmin(v0, a0)));
  e0.y = h2u(pmin(pmin(a0, a2),       pmin(v1, a1)));
  e0.z = h2u(pmin(pmin(a1, a3),       pmin(v2, a2)));
  e0.w = h2u(pmin(pmin(a2, u2h(r0.x)), pmin(v3, a3)));
  e1.x = h2u(pmin(pmin(u2h(l1.w), b1), pmin(w0, b0)));
  e1.y = h2u(pmin(pmin(b0, b2),       pmin(w1, b1)));
  e1.z = h2u(pmin(pmin(b1, b3),       pmin(w2, b2)));
  e1.w = h2u(pmin(pmin(b2, u2h(r1.x)), pmin(w3, b3)));
  *(uint4*)&B[o]      = e0;
  *(uint4*)&B[o + SP] = e1;
}

// sentinel(2.0)->0, identity on [0,1]: t=max(x-1,0); x-=2t (exact in fp16)
__device__ __forceinline__ h2 unsent(h2 x, h2 onev, h2 zerov){
  h2 t = pmax(x - onev, zerov);
  return x - t - t;
}

template<bool BND>
__device__ void pipeline(const float* __restrict__ pred, const int* __restrict__ targ,
                         long base, int gr0, int gc0, int tid,
                         unsigned* A, unsigned* B, h2 val[16], h2 skel[16]) {
  // ---- global -> LDS: 88 rows x 22 quads, word = (pred, targ) ----
  #pragma unroll
  for (int k = 0; k < 8; ++k) {
    int u = tid + (k << 8);
    if (u < 1936) {
      int r = u / 22, q = u - r * 22;
      uint4 w;
      if (!BND) {
        long g = base + (long)(gr0 + r) * IMG + (gc0 + (q << 2));
        float4 pv = *(const float4*)(pred + g);
        int4   tv = *(const int4*)(targ + g);
        h2 a;
        a.x = (_Float16)sigmoidf(pv.x); a.y = (_Float16)(float)tv.x; w.x = h2u(a);
        a.x = (_Float16)sigmoidf(pv.y); a.y = (_Float16)(float)tv.y; w.y = h2u(a);
        a.x = (_Float16)sigmoidf(pv.z); a.y = (_Float16)(float)tv.z; w.z = h2u(a);
        a.x = (_Float16)sigmoidf(pv.w); a.y = (_Float16)(float)tv.w; w.w = h2u(a);
      } else {
        int gr = gr0 + r;
        bool rok = (unsigned)gr < (unsigned)IMG;
        unsigned* wp = (unsigned*)&w;
        #pragma unroll
        for (int i = 0; i < 4; ++i) {
          int gc = gc0 + (q << 2) + i;
          unsigned wv = SEN2;
          if (rok && (unsigned)gc < (unsigned)IMG) {
            long g = base + (long)gr * IMG + gc;
            h2 a; a.x = (_Float16)sigmoidf(pred[g]); a.y = (_Float16)(float)targ[g];
            wv = h2u(a);
          }
          wp[i] = wv;
        }
      }
      *(uint4*)&A[r * SP + 4 + (q << 2)] = w;
    }
  }
  __syncthreads();

  // erode work: 43 tall-2 strips (rows 1..86) x 22 quads = 946 units, j-invariant
  int  eoff[4]; bool eok[4];
  #pragma unroll
  for (int k = 0; k < 4; ++k) {
    int u = tid + (k << 8);
    eok[k] = (u < 946);
    int uc = eok[k] ? u : 0;
    int s = uc / 22, q = uc - s * 22;
    eoff[k] = (1 + (s << 1)) * SP + 4 + (q << 2);
  }

  // interior ownership: 4 rows x 4 px per thread (always in-image)
  const int qc = tid & 15;          // 0..15
  const int rg = tid >> 4;          // 0..15
  const int r0 = HALO + (rg << 2);  // 12..72
  const int wo = 4 + HALO + (qc << 2); // words 16..76

  h2 ep[16];
  #pragma unroll
  for (int t = 0; t < 4; ++t) {
    uint4 c = *(const uint4*)&A[(r0 + t) * SP + wo];
    ep[4*t+0] = u2h(c.x); ep[4*t+1] = u2h(c.y); ep[4*t+2] = u2h(c.z); ep[4*t+3] = u2h(c.w);
  }
  #pragma unroll
  for (int i = 0; i < 16; ++i) { val[i] = ep[i]; skel[i] = (h2)(_Float16)0.0f; }

  const h2 onev  = {(_Float16)1.0f, (_Float16)1.0f};
  const h2 zerov = {(_Float16)0.0f, (_Float16)0.0f};

  for (int j = 0; j < 11; ++j) {
    // ---- erode A -> B ----
    #pragma unroll
    for (int k = 0; k < 4; ++k) if (eok[k]) erode2(A, B, eoff[k]);
    __syncthreads();

    if (BND) {
      if (gr0 < 0)          for (int i = tid; i < 12*SP; i += 256) B[i] = SEN2;
      if (gr0 + 88 > IMG)   for (int i = tid; i < 12*SP; i += 256) B[76*SP + i] = SEN2;
      if (gc0 < 0)          for (int i = tid; i < 88*12; i += 256) { int r = i/12; B[r*SP + 4  + (i - r*12)] = SEN2; }
      if (gc0 + 88 > IMG)   for (int i = tid; i < 88*12; i += 256) { int r = i/12; B[r*SP + 80 + (i - r*12)] = SEN2; }
      __syncthreads();
    }

    // ---- 3x3 dilate of B at own 4x4 px + skel update (reads B only) ----
    h2 H[6][4];
    uint4 cap[4];
    #pragma unroll
    for (int k = 0; k < 6; ++k) {
      int ro = (r0 - 1 + k) * SP + wo;
      uint4 c = *(const uint4*)&B[ro];
      uint4 lq = *(const uint4*)&B[ro - 4];
      uint4 rq = *(const uint4*)&B[ro + 4];
      if (k >= 1 && k <= 4) cap[k-1] = c;          // raw e_j at own rows
      h2 a0=u2h(c.x), a1=u2h(c.y), a2=u2h(c.z), a3=u2h(c.w);
      h2 lw=u2h(lq.w), rx=u2h(rq.x);
      if (BND) {
        a0 = unsent(a0, onev, zerov); a1 = unsent(a1, onev, zerov);
        a2 = unsent(a2, onev, zerov); a3 = unsent(a3, onev, zerov);
        lw = unsent(lw, onev, zerov); rx = unsent(rx, onev, zerov);
      }
      H[k][0] = pmax(pmax(lw, a1), a0);
      H[k][1] = pmax(pmax(a0, a2), a1);
      H[k][2] = pmax(pmax(a1, a3), a2);
      H[k][3] = pmax(pmax(a2, rx), a3);
    }
    #pragma unroll
    for (int t = 0; t < 4; ++t) {
      #pragma unroll
      for (int i = 0; i < 4; ++i) {
        h2 m = pmax(pmax(H[t][i], H[t+1][i]), H[t+2][i]);
        h2 d = pmax(ep[4*t+i] - m, zerov);          // relu(e_prev - open)
        h2 x = d - skel[4*t+i] * d;                 // skel=0 at j=0 -> x=d (init)
        skel[4*t+i] = skel[4*t+i] + pmax(x, zerov);
      }
    }
    #pragma unroll
    for (int t = 0; t < 4; ++t) {
      ep[4*t+0] = u2h(cap[t].x); ep[4*t+1] = u2h(cap[t].y);
      ep[4*t+2] = u2h(cap[t].z); ep[4*t+3] = u2h(cap[t].w);
    }
    // no barrier needed: dilate read only B; next erode writes old A whose
    // readers all passed the post-erode barrier.
    unsigned* t = A; A = B; B = t;
  }
  __syncthreads();
}

__global__ __launch_bounds__(256)
void cl_dice_main(const float* __restrict__ pred, const int* __restrict__ targ,
                  float* __restrict__ ws) {
  __shared__ alignas(16) unsigned sA[LDSW];
  __shared__ alignas(16) unsigned sB[LDSW];
  const int tid = threadIdx.x;
  const int gr0 = blockIdx.y * TILE - HALO;
  const int gc0 = blockIdx.x * TILE - HALO;
  const long base = (long)blockIdx.z * (long)(IMG * IMG);

  h2 val[16], skel[16];
  const bool bnd = (blockIdx.x == 0) | (blockIdx.x == gridDim.x - 1) |
                   (blockIdx.y == 0) | (blockIdx.y == gridDim.y - 1);
  if (!bnd) pipeline<false>(pred, targ, base, gr0, gc0, tid, sA, sB, val, skel);
  else      pipeline<true >(pred, targ, base, gr0, gc0, tid, sA, sB, val, skel);

  // per-thread partials: word = (pred, targ); skel = (skel_p, skel_t)
  float s[7] = {0, 0, 0, 0, 0, 0, 0};
  #pragma unroll
  for (int i = 0; i < 16; ++i) {
    float p = (float)val[i].x,  t = (float)val[i].y;
    float kp = (float)skel[i].x, kt = (float)skel[i].y;
    s[0] += kp;       s[1] += kp * t;
    s[2] += kt;       s[3] += kt * p;
    s[4] += p * t;    s[5] += p;       s[6] += t;
  }

  float* red = (float*)sA;
  #pragma unroll
  for (int k = 0; k < 7; ++k) {
    float v = s[k];
    v += __shfl_down(v, 32); v += __shfl_down(v, 16); v += __shfl_down(v, 8);
    v += __shfl_down(v, 4);  v += __shfl_down(v, 2);  v += __shfl_down(v, 1);
    if ((tid & 63) == 0) red[(tid >> 6) * 8 + k] = v;
  }
  __syncthreads();
  if (tid < 7) {
    float v = red[tid] + red[8 + tid] + red[16 + tid] + red[24 + tid];
    int blk = (blockIdx.z * gridDim.y + blockIdx.y) * gridDim.x + blockIdx.x;
    ws[blk * 8 + tid] = v;
  }
}

__global__ __launch_bounds__(256)
void cl_dice_finalize(const float* __restrict__ ws, float* __restrict__ out, int nblk) {
  __shared__ float red[4][8];
  int tid = threadIdx.x;
  float acc[7] = {0, 0, 0, 0, 0, 0, 0};
  for (int i = tid; i < nblk; i += 256) {
    #pragma unroll
    for (int k = 0; k < 7; ++k) acc[k] += ws[i * 8 + k];
  }
  #pragma unroll
  for (int k = 0; k < 7; ++k) {
    float v = acc[k];
    v += __shfl_down(v, 32); v += __shfl_down(v, 16); v += __shfl_down(v, 8);
    v += __shfl_down(v, 4);  v += __shfl_down(v, 2);  v += __shfl_down(v, 1);
    if ((tid & 63) == 0) red[tid >> 6][k] = v;
  }
  __syncthreads();
  if (tid == 0) {
    float t0[7];
    #pragma unroll
    for (int k = 0; k < 7; ++k)
      t0[k] = red[0][k] + red[1][k] + red[2][k] + red[3][k];
    float sum_sp = t0[0], sum_spt = t0[1], sum_st = t0[2], sum_stp = t0[3];
    float inter  = t0[4], sum_p   = t0[5], sum_t  = t0[6];
    float tprec = (sum_spt + 1.0f) / (sum_sp + 1.0f);
    float tsens = (sum_stp + 1.0f) / (sum_st + 1.0f);
    float cl    = 2.0f * tprec * tsens / (tprec + tsens + 1e-7f);
    float dice  = (2.0f * inter + 1.0f) / (sum_p + sum_t + 1.0f);
    out[0] = 1.0f - 0.5f * (dice + cl);
  }
}

extern "C" void kernel_launch(void* const* d_in, const int* in_sizes, int n_in,
                              void* d_out, int out_size, void* d_ws, size_t ws_size,
                              hipStream_t stream) {
  const float* pred = (const float*)d_in[0];
  const int*   targ = (const int*)d_in[1];
  float* ws  = (float*)d_ws;
  float* out = (float*)d_out;

  const int B = in_sizes[0] / (IMG * IMG);     // 8
  dim3 grid(IMG / TILE, IMG / TILE, B);        // 16 x 16 x 8 = 2048 blocks
  cl_dice_main<<<grid, 256, 0, stream>>>(pred, targ, ws);

  const int nblk = (IMG / TILE) * (IMG / TILE) * B;
  cl_dice_finalize<<<1, 256, 0, stream>>>(ws, out, nblk);
}

// Round 8
// 249.569 us; speedup vs baseline: 1.1833x; 1.0775x over previous
//
#include <hip/hip_runtime.h>
#include <math.h>

#define IMG  1024
#define TILE 64
#define HALO 12
#define SPP  52             // pred words/row: 2 front pad + 44 data (words 2..45) + 6 rear pad
#define NPRED (88*SPP)      // 4576 words/buffer
#define SEN2 0x40004000u    // (2.0h,2.0h) sentinel = +inf (all real values <= 1)

// pred: fp16 pair-packed, 2 px/word. targ: binary bit-packed, 32 px/word
// (target is exactly {0,1}; erode=AND-5, dilate=OR-9, skel_t=OR(e_prev&~dil)).
typedef _Float16 h2 __attribute__((ext_vector_type(2)));
union UH { unsigned u; h2 h; };
__device__ __forceinline__ h2 u2h(unsigned u){ UH x; x.u=u; return x.h; }
__device__ __forceinline__ unsigned h2u(h2 h){ UH x; x.h=h; return x.u; }
__device__ __forceinline__ h2 pmin(h2 a, h2 b){ return __builtin_elementwise_min(a,b); }
__device__ __forceinline__ h2 pmax(h2 a, h2 b){ return __builtin_elementwise_max(a,b); }
// (lo_src.hi, hi_src.lo) — one v_alignbit_b32
__device__ __forceinline__ h2 funnel(h2 hi_src, h2 lo_src){
  return u2h((h2u(lo_src)>>16) | (h2u(hi_src)<<16));
}
__device__ __forceinline__ float sigmoidf(float x){ return 1.0f/(1.0f+__expf(-x)); }
// sentinel(2.0)->0, identity on [0,1]: t=max(x-1,0); x-=2t (exact in fp16)
__device__ __forceinline__ h2 unsent(h2 x, h2 onev, h2 zerov){
  h2 t = pmax(x-onev, zerov); return x - t - t;
}
// 8 bits starting at bp (<96) from a 3-word row
__device__ __forceinline__ unsigned extract8(unsigned w0, unsigned w1, unsigned w2, int bp){
  unsigned long long lo = (unsigned long long)w0 | ((unsigned long long)w1<<32);
  unsigned long long hi = (unsigned long long)w1 | ((unsigned long long)w2<<32);
  unsigned a = (unsigned)(lo >> bp);
  unsigned b = (unsigned)(hi >> (bp & 31));
  return ((bp < 32) ? a : b) & 0xFFu;
}

// 5-pt cross erode of 8 px x 2 rows at word offset o (16B aligned).
// 4 b128 + 4 b32 reads, 2 b128 writes.
__device__ __forceinline__ void erode2p(const unsigned* A, unsigned* B, int o){
  uint4 up = *(const uint4*)&A[o - SPP];
  uint4 c0 = *(const uint4*)&A[o];
  uint4 c1 = *(const uint4*)&A[o + SPP];
  uint4 dn = *(const uint4*)&A[o + 2*SPP];
  unsigned l0 = A[o-1], l1 = A[o+SPP-1], rr0 = A[o+4], rr1 = A[o+SPP+4];
  h2 a0=u2h(c0.x),a1=u2h(c0.y),a2=u2h(c0.z),a3=u2h(c0.w);
  h2 b0=u2h(c1.x),b1=u2h(c1.y),b2=u2h(c1.z),b3=u2h(c1.w);
  h2 va0=pmin(u2h(up.x),b0), va1=pmin(u2h(up.y),b1), va2=pmin(u2h(up.z),b2), va3=pmin(u2h(up.w),b3);
  h2 vb0=pmin(a0,u2h(dn.x)), vb1=pmin(a1,u2h(dn.y)), vb2=pmin(a2,u2h(dn.z)), vb3=pmin(a3,u2h(dn.w));
  h2 f0=funnel(a0,u2h(l0)), f1=funnel(a1,a0), f2=funnel(a2,a1), f3=funnel(a3,a2), f4=funnel(u2h(rr0),a3);
  h2 g0=funnel(b0,u2h(l1)), g1=funnel(b1,b0), g2=funnel(b2,b1), g3=funnel(b3,b2), g4=funnel(u2h(rr1),b3);
  uint4 e0,e1;
  e0.x=h2u(pmin(pmin(f0,f1),pmin(va0,a0)));
  e0.y=h2u(pmin(pmin(f1,f2),pmin(va1,a1)));
  e0.z=h2u(pmin(pmin(f2,f3),pmin(va2,a2)));
  e0.w=h2u(pmin(pmin(f3,f4),pmin(va3,a3)));
  e1.x=h2u(pmin(pmin(g0,g1),pmin(vb0,b0)));
  e1.y=h2u(pmin(pmin(g1,g2),pmin(vb1,b1)));
  e1.z=h2u(pmin(pmin(g2,g3),pmin(vb2,b2)));
  e1.w=h2u(pmin(pmin(g3,g4),pmin(vb3,b3)));
  *(uint4*)&B[o]      = e0;
  *(uint4*)&B[o+SPP]  = e1;
}

template<bool BND>
__device__ void pipeline(const float* __restrict__ pred, const int* __restrict__ targ,
                         long base, int gr0, int gc0, int tid,
                         unsigned* PA, unsigned* PB, unsigned* TAi, unsigned* TBi,
                         unsigned* sK,
                         h2 val[8], h2 skel[8], unsigned &tbits, unsigned &skbits) {
  // ---- global -> LDS ----
  if (!BND) {
    #pragma unroll
    for (int k=0;k<4;++k){
      int u = tid + (k<<8);
      if (u < 968) {                       // 88 rows x 11 groups of 8 px
        int r = u/11, q = u - r*11;
        long g = base + (long)(gr0+r)*IMG + gc0 + (q<<3);
        float4 pa = *(const float4*)(pred+g);
        float4 pb = *(const float4*)(pred+g+4);
        h2 w0 = {(_Float16)sigmoidf(pa.x), (_Float16)sigmoidf(pa.y)};
        h2 w1 = {(_Float16)sigmoidf(pa.z), (_Float16)sigmoidf(pa.w)};
        h2 w2 = {(_Float16)sigmoidf(pb.x), (_Float16)sigmoidf(pb.y)};
        h2 w3 = {(_Float16)sigmoidf(pb.z), (_Float16)sigmoidf(pb.w)};
        int o = r*SPP + 2 + (q<<2);
        uint2 d0; d0.x=h2u(w0); d0.y=h2u(w1);
        uint2 d1; d1.x=h2u(w2); d1.y=h2u(w3);
        *(uint2*)&PA[o]   = d0;
        *(uint2*)&PA[o+2] = d1;
      }
    }
    #pragma unroll
    for (int k=0;k<2;++k){
      int u = tid + (k<<8);
      if (u < 264) {                       // 88 rows x 3 bit-words
        int r = u/3, w = u - r*3;
        long g = base + (long)(gr0+r)*IMG + gc0 + (w<<5);
        unsigned bits = 0;
        #pragma unroll
        for (int i=0;i<8;++i){
          if (w < 2 || i < 6) {
            int4 tv = *(const int4*)(targ + g + (i<<2));
            unsigned nib = (unsigned)(tv.x!=0) | ((unsigned)(tv.y!=0)<<1)
                         | ((unsigned)(tv.z!=0)<<2) | ((unsigned)(tv.w!=0)<<3);
            bits |= nib << (i<<2);
          }
        }
        if (w==2) bits |= 0xFF000000u;     // pseudo px 88..95: erode-neutral 1
        TAi[u] = bits;
      }
    }
  } else {
    for (int i=tid; i<88*44; i+=256){
      int r = i/44, wd = i - r*44;
      int gr = gr0 + r;
      bool rok = (unsigned)gr < (unsigned)IMG;
      int gca = gc0 + (wd<<1), gcb = gca + 1;
      _Float16 va = (_Float16)2.0f, vb = (_Float16)2.0f;
      if (rok && (unsigned)gca < (unsigned)IMG) va = (_Float16)sigmoidf(pred[base + (long)gr*IMG + gca]);
      if (rok && (unsigned)gcb < (unsigned)IMG) vb = (_Float16)sigmoidf(pred[base + (long)gr*IMG + gcb]);
      h2 w; w.x = va; w.y = vb;
      PA[r*SPP + 2 + wd] = h2u(w);
    }
    for (int u=tid; u<264; u+=256){
      int r = u/3, w = u - r*3;
      int gr = gr0 + r;
      bool rok = (unsigned)gr < (unsigned)IMG;
      unsigned bits = 0;
      for (int b=0;b<32;++b){
        int c = (w<<5) + b;
        unsigned bit = 1;                  // OOB / pseudo -> erode-neutral 1
        if (c < 88) {
          int gc = gc0 + c;
          if (rok && (unsigned)gc < (unsigned)IMG) bit = (unsigned)(targ[base+(long)gr*IMG+gc] != 0);
        }
        bits |= bit << b;
      }
      TAi[u] = bits;
    }
  }
  __syncthreads();

  // col validity masks (BND)
  unsigned cm0=~0u, cm1=~0u, cm2=0x00FFFFFFu;
  bool colO = false;
  if (BND) {
    int lo = (-gc0 > 0) ? -gc0 : 0;
    int hi = (IMG - gc0 < 88) ? (IMG - gc0) : 88;
    colO = (lo > 0) || (hi < 88);
    unsigned m[3];
    #pragma unroll
    for (int w=0; w<3; ++w){
      int l = lo - (w<<5); if (l<0) l=0;
      int h = hi - (w<<5); if (h>32) h=32;
      unsigned mm = 0;
      if (h > l) {
        unsigned top = (h>=32)? ~0u : ((1u<<h)-1u);
        unsigned bot = (l<=0)? 0u : ((1u<<l)-1u);
        mm = top & ~bot;
      }
      m[w]=mm;
    }
    cm0=m[0]; cm1=m[1]; cm2=m[2] & 0x00FFFFFF;
  }

  // j-invariant pred erode offsets: 43 tall-2 strips x 12 quads = 516 units
  int eo0, eo1, eo2 = 0;
  { int u=tid;     int s=u/12, q=u-s*12; eo0 = (1+(s<<1))*SPP + (q<<2); }
  { int u=tid+256; int s=u/12, q=u-s*12; eo1 = (1+(s<<1))*SPP + (q<<2); }
  const bool eex = (tid < 4);
  if (eex) { int u=tid+512; int s=u/12, q=u-s*12; eo2 = (1+(s<<1))*SPP + (q<<2); }
  // targ erode: unit u -> row 1+u/3, word u%3 -> offset 3+u
  const int to  = 3 + tid;
  const int twd = tid - (tid/3)*3;
  const bool tex = (tid < 2);
  const int to2  = 3 + 256 + tid;
  const int twd2 = (256+tid) - ((256+tid)/3)*3;

  // interior ownership: 2 rows x 8 px per thread
  const int qc = tid & 7;
  const int rg = tid >> 3;
  const int r0 = HALO + (rg<<1);      // 12..74
  const int wq = 8 + (qc<<2);         // words 8..36
  const int bp = 12 + (qc<<3);        // bit position of first own px

  h2 ep[8];
  {
    uint4 a0 = *(const uint4*)&PA[r0*SPP + wq];
    uint4 a1 = *(const uint4*)&PA[(r0+1)*SPP + wq];
    ep[0]=u2h(a0.x); ep[1]=u2h(a0.y); ep[2]=u2h(a0.z); ep[3]=u2h(a0.w);
    ep[4]=u2h(a1.x); ep[5]=u2h(a1.y); ep[6]=u2h(a1.z); ep[7]=u2h(a1.w);
    #pragma unroll
    for (int i=0;i<8;++i){ val[i]=ep[i]; skel[i]=(h2)(_Float16)0.0f; }
  }
  {
    int oa = r0*3, ob = (r0+1)*3;
    tbits = extract8(TAi[oa],TAi[oa+1],TAi[oa+2],bp)
          | (extract8(TAi[ob],TAi[ob+1],TAi[ob+2],bp) << 8);
  }
  // targ dilate state (threads 0..63, one tile-row each)
  unsigned tp0=0,tp1=0,tp2=0, sk0=0,sk1=0,sk2=0;
  const bool td = (tid < 64);
  const int tro = (12 + tid)*3;
  if (td) { tp0=TAi[tro]; tp1=TAi[tro+1]; tp2=TAi[tro+2]; }

  const h2 onev  = {(_Float16)1.0f,(_Float16)1.0f};
  const h2 zerov = {(_Float16)0.0f,(_Float16)0.0f};
  unsigned *A=PA, *B=PB, *Ta=TAi, *Tb=TBi;

  for (int j=0;j<11;++j){
    // ---- erode (pred fp16 + targ binary) A -> B ----
    erode2p(A,B,eo0);
    erode2p(A,B,eo1);
    if (eex) erode2p(A,B,eo2);
    {
      unsigned own=Ta[to], up=Ta[to-3], dn=Ta[to+3];
      unsigned le = (twd>0)? Ta[to-1] : ~0u;
      unsigned ri = (twd<2)? Ta[to+1] : ~0u;
      unsigned h = own & ((own>>1)|(ri<<31)) & ((own<<1)|(le>>31));
      Tb[to] = h & up & dn;
    }
    if (tex) {
      unsigned own=Ta[to2], up=Ta[to2-3], dn=Ta[to2+3];
      unsigned le = (twd2>0)? Ta[to2-1] : ~0u;
      unsigned ri = (twd2<2)? Ta[to2+1] : ~0u;
      unsigned h = own & ((own>>1)|(ri<<31)) & ((own<<1)|(le>>31));
      Tb[to2] = h & up & dn;
    }
    __syncthreads();

    if (BND) {  // re-stamp OOB to erode-neutral sentinel
      if (gr0 < 0) {
        for (int i=tid;i<12*44;i+=256){ int r=i/44; B[r*SPP+2+(i-r*44)] = SEN2; }
        if (tid < 36) Tb[tid] = ~0u;
      }
      if (gr0 + 88 > IMG) {
        for (int i=tid;i<12*44;i+=256){ int r=i/44; B[(76+r)*SPP+2+(i-r*44)] = SEN2; }
        if (tid < 36) Tb[228+tid] = ~0u;
      }
      if (colO) {
        if (gc0 < 0)
          for (int i=tid;i<88*6;i+=256){ int r=i/6; B[r*SPP+2+(i-r*6)] = SEN2; }
        if (gc0 + 88 > IMG)
          for (int i=tid;i<88*6;i+=256){ int r=i/6; B[r*SPP+40+(i-r*6)] = SEN2; }
        for (int i=tid;i<264;i+=256){
          int r=i/3, w=i-r*3;
          unsigned nm = (w==0)?~cm0:((w==1)?~cm1:~cm2);
          Tb[i] |= nm;
        }
      }
      __syncthreads();
    }

    // ---- pred 3x3 dilate at own 2x8 px + skel update (reads B only) ----
    h2 H[4][4];
    uint4 cap0, cap1;
    #pragma unroll
    for (int k=0;k<4;++k){
      int ro = (r0-1+k)*SPP + wq;
      uint4 c = *(const uint4*)&B[ro];
      h2 lw = u2h(B[ro-1]);
      h2 rw = u2h(B[ro+4]);
      if (k==1) cap0 = c;                 // raw e_j at own rows -> next ep
      if (k==2) cap1 = c;
      h2 a0=u2h(c.x),a1=u2h(c.y),a2=u2h(c.z),a3=u2h(c.w);
      if (BND){
        a0=unsent(a0,onev,zerov); a1=unsent(a1,onev,zerov);
        a2=unsent(a2,onev,zerov); a3=unsent(a3,onev,zerov);
        lw=unsent(lw,onev,zerov); rw=unsent(rw,onev,zerov);
      }
      h2 f0=funnel(a0,lw), f1=funnel(a1,a0), f2=funnel(a2,a1), f3=funnel(a3,a2), f4=funnel(rw,a3);
      H[k][0]=pmax(pmax(f0,f1),a0);
      H[k][1]=pmax(pmax(f1,f2),a1);
      H[k][2]=pmax(pmax(f2,f3),a2);
      H[k][3]=pmax(pmax(f3,f4),a3);
    }
    #pragma unroll
    for (int i=0;i<4;++i){
      h2 m0 = pmax(pmax(H[0][i],H[1][i]),H[2][i]);
      h2 m1 = pmax(pmax(H[1][i],H[2][i]),H[3][i]);
      h2 d0 = pmax(ep[i]-m0, zerov);
      h2 d1 = pmax(ep[4+i]-m1, zerov);
      h2 x0 = d0 - skel[i]*d0;
      h2 x1 = d1 - skel[4+i]*d1;
      skel[i]   = skel[i]   + pmax(x0, zerov);
      skel[4+i] = skel[4+i] + pmax(x1, zerov);
    }
    ep[0]=u2h(cap0.x); ep[1]=u2h(cap0.y); ep[2]=u2h(cap0.z); ep[3]=u2h(cap0.w);
    ep[4]=u2h(cap1.x); ep[5]=u2h(cap1.y); ep[6]=u2h(cap1.z); ep[7]=u2h(cap1.w);

    // ---- targ dilate + skel_t (threads 0..63) ----
    if (td) {
      unsigned o0=Tb[tro], o1=Tb[tro+1], o2=Tb[tro+2];
      unsigned u0=Tb[tro-3], u1=Tb[tro-2], u2=Tb[tro-1];
      unsigned n0=Tb[tro+3], n1=Tb[tro+4], n2=Tb[tro+5];
      unsigned v0,v1,v2;
      if (BND){
        unsigned mu = ((unsigned)(gr0 + 11 + tid) < (unsigned)IMG) ? ~0u : 0u;
        unsigned md = ((unsigned)(gr0 + 13 + tid) < (unsigned)IMG) ? ~0u : 0u;
        v0 = ((u0&mu)|o0|(n0&md)) & cm0;
        v1 = ((u1&mu)|o1|(n1&md)) & cm1;
        v2 = ((u2&mu)|o2|(n2&md)) & cm2;
      } else {
        v0 = u0|o0|n0; v1 = u1|o1|n1; v2 = u2|o2|n2;
      }
      unsigned d0 = v0 | (v0<<1) | (v0>>1) | (v1<<31);
      unsigned d1 = v1 | (v1<<1) | (v0>>31) | (v1>>1) | (v2<<31);
      unsigned d2 = v2 | (v2<<1) | (v1>>31) | (v2>>1);
      sk0 |= tp0 & ~d0;
      sk1 |= tp1 & ~d1;
      sk2 |= tp2 & ~d2;
      tp0 = o0; tp1 = o1; tp2 = o2;
    }
    unsigned* t1 = A;  A = B;  B = t1;
    unsigned* t2 = Ta; Ta = Tb; Tb = t2;
  }

  if (td){ sK[3*tid] = sk0; sK[3*tid+1] = sk1; sK[3*tid+2] = sk2; }
  __syncthreads();
  {
    int o = (r0-12)*3;
    skbits = extract8(sK[o],sK[o+1],sK[o+2],bp)
           | (extract8(sK[o+3],sK[o+4],sK[o+5],bp) << 8);
  }
}

__global__ __launch_bounds__(256,4)
void cl_dice_main(const float* __restrict__ pred, const int* __restrict__ targ,
                  float* __restrict__ ws) {
  __shared__ alignas(16) unsigned sPA[NPRED];
  __shared__ alignas(16) unsigned sPB[NPRED];
  __shared__ unsigned sTA[264], sTB[264], sK[192];
  const int tid = threadIdx.x;
  const int gr0 = blockIdx.y * TILE - HALO;
  const int gc0 = blockIdx.x * TILE - HALO;
  const long base = (long)blockIdx.z * (long)(IMG * IMG);

  h2 val[8], skel[8]; unsigned tbits, skbits;
  const bool bnd = (blockIdx.x == 0) | (blockIdx.x == gridDim.x - 1) |
                   (blockIdx.y == 0) | (blockIdx.y == gridDim.y - 1);
  if (!bnd) pipeline<false>(pred, targ, base, gr0, gc0, tid, sPA, sPB, sTA, sTB, sK, val, skel, tbits, skbits);
  else      pipeline<true >(pred, targ, base, gr0, gc0, tid, sPA, sPB, sTA, sTB, sK, val, skel, tbits, skbits);

  float s[7] = {0,0,0,0,0,0,0};
  #pragma unroll
  for (int k=0;k<8;++k){
    int bb = ((k>>2)<<3) + ((k&3)<<1);
    float p0=(float)val[k].x,  p1=(float)val[k].y;
    float a0=(float)skel[k].x, a1=(float)skel[k].y;
    float t0=(float)((tbits>>bb)&1u),    t1=(float)((tbits>>(bb+1))&1u);
    float b0=(float)((skbits>>bb)&1u),   b1=(float)((skbits>>(bb+1))&1u);
    s[0]+=a0+a1;        s[1]+=a0*t0+a1*t1;
    s[2]+=b0+b1;        s[3]+=b0*p0+b1*p1;
    s[4]+=p0*t0+p1*t1;  s[5]+=p0+p1;  s[6]+=t0+t1;
  }

  float* red = (float*)sPA;
  #pragma unroll
  for (int k=0;k<7;++k){
    float v = s[k];
    v += __shfl_down(v,32); v += __shfl_down(v,16); v += __shfl_down(v,8);
    v += __shfl_down(v,4);  v += __shfl_down(v,2);  v += __shfl_down(v,1);
    if ((tid & 63) == 0) red[(tid>>6)*8 + k] = v;
  }
  __syncthreads();
  if (tid < 7) {
    float v = red[tid] + red[8+tid] + red[16+tid] + red[24+tid];
    int blk = (blockIdx.z * gridDim.y + blockIdx.y) * gridDim.x + blockIdx.x;
    ws[blk*8 + tid] = v;
  }
}

__global__ __launch_bounds__(256)
void cl_dice_finalize(const float* __restrict__ ws, float* __restrict__ out, int nblk) {
  __shared__ float red[4][8];
  int tid = threadIdx.x;
  float acc[7] = {0,0,0,0,0,0,0};
  for (int i=tid; i<nblk; i+=256) {
    #pragma unroll
    for (int k=0;k<7;++k) acc[k] += ws[i*8 + k];
  }
  #pragma unroll
  for (int k=0;k<7;++k){
    float v = acc[k];
    v += __shfl_down(v,32); v += __shfl_down(v,16); v += __shfl_down(v,8);
    v += __shfl_down(v,4);  v += __shfl_down(v,2);  v += __shfl_down(v,1);
    if ((tid & 63) == 0) red[tid>>6][k] = v;
  }
  __syncthreads();
  if (tid == 0) {
    float t0[7];
    #pragma unroll
    for (int k=0;k<7;++k) t0[k] = red[0][k] + red[1][k] + red[2][k] + red[3][k];
    float sum_sp = t0[0], sum_spt = t0[1], sum_st = t0[2], sum_stp = t0[3];
    float inter  = t0[4], sum_p   = t0[5], sum_t  = t0[6];
    float tprec = (sum_spt + 1.0f) / (sum_sp + 1.0f);
    float tsens = (sum_stp + 1.0f) / (sum_st + 1.0f);
    float cl    = 2.0f * tprec * tsens / (tprec + tsens + 1e-7f);
    float dice  = (2.0f * inter + 1.0f) / (sum_p + sum_t + 1.0f);
    out[0] = 1.0f - 0.5f * (dice + cl);
  }
}

extern "C" void kernel_launch(void* const* d_in, const int* in_sizes, int n_in,
                              void* d_out, int out_size, void* d_ws, size_t ws_size,
                              hipStream_t stream) {
  const float* pred = (const float*)d_in[0];
  const int*   targ = (const int*)d_in[1];
  float* ws  = (float*)d_ws;
  float* out = (float*)d_out;

  const int B = in_sizes[0] / (IMG * IMG);     // 8
  dim3 grid(IMG / TILE, IMG / TILE, B);        // 16 x 16 x 8 = 2048 blocks
  cl_dice_main<<<grid, 256, 0, stream>>>(pred, targ, ws);

  const int nblk = (IMG / TILE) * (IMG / TILE) * B;
  cl_dice_finalize<<<1, 256, 0, stream>>>(ws, out, nblk);
}